// Round 2
// baseline (1216.095 us; speedup 1.0000x reference)
//
#include <hip/hip_runtime.h>
#include <math.h>

#define NN 50000
#define EE 400000

// ---------- K1: h1 = ScaledSiLU(x @ W_x1 + b_x1)  [NN,128]x[128,64] ----------
__global__ __launch_bounds__(256) void k_h1(
    const float* __restrict__ x, const float* __restrict__ W,
    const float* __restrict__ b, float* __restrict__ h1)
{
    __shared__ float xs[32 * 128];
    int t = threadIdx.x;
    int base = blockIdx.x * 32;
    const float4* xv = (const float4*)x;
    for (int idx = t; idx < 1024; idx += 256) {
        int r = idx >> 5, c = idx & 31;
        int row = base + r; if (row >= NN) row = NN - 1;
        ((float4*)xs)[r * 32 + c] = xv[(size_t)row * 32 + c];
    }
    __syncthreads();
    int c = t & 63, rr = t >> 6;
    float acc[8] = {};
    for (int k = 0; k < 128; ++k) {
        float wv = W[k * 64 + c];
        #pragma unroll
        for (int q = 0; q < 8; ++q) acc[q] += xs[(rr + 4 * q) * 128 + k] * wv;
    }
    float bb = b[c];
    #pragma unroll
    for (int q = 0; q < 8; ++q) {
        int row = base + rr + 4 * q;
        if (row < NN) {
            float z = acc[q] + bb;
            h1[(size_t)row * 64 + c] = z / (1.f + expf(-z)) * (1.f / 0.6f);  // ScaledSiLU
        }
    }
}

// ---------- K2: out[n,384] = A[n,K] @ W[K,384] + b  (f32) ----------
template <int K>
__global__ __launch_bounds__(256) void k_gemm384(
    const float* __restrict__ A, const float* __restrict__ W,
    const float* __restrict__ b, float* __restrict__ out)
{
    __shared__ float as[32 * K];
    int t = threadIdx.x;
    int base = blockIdx.x * 32;
    const float4* av = (const float4*)A;
    const int K4 = K / 4;
    for (int idx = t; idx < 32 * K4; idx += 256) {
        int r = idx / K4, c = idx % K4;
        int row = base + r; if (row >= NN) row = NN - 1;
        ((float4*)as)[r * K4 + c] = av[(size_t)row * K4 + c];
    }
    __syncthreads();
    int c = t & 63, rr = t >> 6;
    float acc[8][6] = {};
    for (int k = 0; k < K; ++k) {
        float wv[6];
        #pragma unroll
        for (int m = 0; m < 6; ++m) wv[m] = W[k * 384 + c + 64 * m];
        #pragma unroll
        for (int q = 0; q < 8; ++q) {
            float a = as[(rr + 4 * q) * K + k];
            #pragma unroll
            for (int m = 0; m < 6; ++m) acc[q][m] += a * wv[m];
        }
    }
    float bb[6];
    #pragma unroll
    for (int m = 0; m < 6; ++m) bb[m] = b[c + 64 * m];
    #pragma unroll
    for (int q = 0; q < 8; ++q) {
        int row = base + rr + 4 * q;
        if (row < NN) {
            #pragma unroll
            for (int m = 0; m < 6; ++m)
                out[(size_t)row * 384 + c + 64 * m] = acc[q][m] + bb[m];
        }
    }
}

// ---------- K3: per-edge fused rbf GEMV + msg + scatter-add (f32 atomics into d_out) ----------
__global__ __launch_bounds__(256) void k_edge(
    const float* __restrict__ ef, const float* __restrict__ ev,
    const int* __restrict__ eidx,
    const float* __restrict__ We, const float* __restrict__ be,
    const float* __restrict__ xd, const float* __restrict__ xh,
    const float* __restrict__ vec,
    float* __restrict__ dx, float* __restrict__ dvec)
{
    __shared__ float efs[32 * 64];
    __shared__ float evs[96];
    __shared__ int js[32], is_[32];
    int t = threadIdx.x;
    int ebase = blockIdx.x * 32;
    const float4* efv = (const float4*)ef;
    for (int idx = t; idx < 512; idx += 256)
        ((float4*)efs)[idx] = efv[(size_t)ebase * 16 + idx];
    if (t < 32) { js[t] = eidx[ebase + t]; is_[t] = eidx[(size_t)EE + ebase + t]; }
    if (t < 96) evs[t] = ev[(size_t)ebase * 3 + t];
    __syncthreads();
    int c = t & 63, w = t >> 6;
    // rbf GEMV: edges (4*r + w), cols c + 64*m
    float acc[8][6] = {};
    for (int k = 0; k < 64; ++k) {
        float wv[6];
        #pragma unroll
        for (int m = 0; m < 6; ++m) wv[m] = We[k * 384 + c + 64 * m];
        #pragma unroll
        for (int r = 0; r < 8; ++r) {
            float f = efs[(4 * r + w) * 64 + k];   // wave-uniform -> LDS broadcast
            #pragma unroll
            for (int m = 0; m < 6; ++m) acc[r][m] += f * wv[m];
        }
    }
    float bb[6];
    #pragma unroll
    for (int m = 0; m < 6; ++m) bb[m] = be[c + 64 * m];
    const float IS3 = 0.57735026918962576f;   // 1/sqrt(3)
    const float ISH = 0.08838834764831845f;   // 1/sqrt(128)
    for (int r = 0; r < 8; ++r) {
        int e = 4 * r + w;
        int j = js[e], i = is_[e];
        size_t jb = (size_t)j * 384, ib = (size_t)i * 384;
        float msg[6];
        #pragma unroll
        for (int m = 0; m < 6; ++m) {
            int col = c + 64 * m;
            float rbf = acc[r][m] + bb[m];
            float xdv = xd[jb + col] + xd[ib + col];
            msg[m] = xh[jb + col] * xdv * rbf * IS3;
        }
        #pragma unroll
        for (int d = 0; d < 3; ++d) {
            float ed = evs[e * 3 + d];
            float v0 = vec[jb + d * 128 + c];
            float v1 = vec[jb + d * 128 + c + 64];
            unsafeAtomicAdd(&dvec[ib + d * 128 + c],      (msg[0] * v0 + msg[2] * ed) * ISH);
            unsafeAtomicAdd(&dvec[ib + d * 128 + c + 64], (msg[1] * v1 + msg[3] * ed) * ISH);
        }
        unsafeAtomicAdd(&dx[(size_t)i * 128 + c],      msg[4]);
        unsafeAtomicAdd(&dx[(size_t)i * 128 + c + 64], msg[5]);
    }
}

// ---------- K4: vector activation, in-place on d_vec region, one wave per node ----------
__global__ __launch_bounds__(256) void k_act(
    float* vio, const float* __restrict__ Wl, const float* __restrict__ Wg)
{
    __shared__ float vs[4 * 384];
    __shared__ float wg[128];
    int t = threadIdx.x;
    if (t < 128) wg[t] = Wg[t];
    int w = t >> 6, l = t & 63;
    for (int it = 0; it < 4; ++it) {
        __syncthreads();               // prior iter's readers done before vs overwrite
        int nb = blockIdx.x * 16 + it * 4;          // 3125*16 = 50000 exact
        const float4* vsrc = (const float4*)(vio + (size_t)nb * 384);
        float4* vdst = (float4*)vs;
        for (int idx = t; idx < 384; idx += 256) vdst[idx] = vsrc[idx];
        __syncthreads();
        const float* v = &vs[w * 384];
        // gvec[d] = sum_h v[d][h] * wg[h]  (wave reduce)
        float g0 = v[l] * wg[l] + v[l + 64] * wg[l + 64];
        float g1 = v[128 + l] * wg[l] + v[128 + l + 64] * wg[l + 64];
        float g2 = v[256 + l] * wg[l] + v[256 + l + 64] * wg[l + 64];
        #pragma unroll
        for (int off = 32; off > 0; off >>= 1) {
            g0 += __shfl_xor(g0, off, 64);
            g1 += __shfl_xor(g1, off, 64);
            g2 += __shfl_xor(g2, off, 64);
        }
        // lvec[d][col], col = l, l+64 ; Wl streamed from global (L2-resident, 64KB)
        float a[3][2] = {};
        #pragma unroll 4
        for (int h = 0; h < 128; ++h) {
            float w0 = Wl[h * 128 + l];
            float w1 = Wl[h * 128 + l + 64];
            float v0 = v[h], v1 = v[128 + h], v2 = v[256 + h];
            a[0][0] += v0 * w0; a[0][1] += v0 * w1;
            a[1][0] += v1 * w0; a[1][1] += v1 * w1;
            a[2][0] += v2 * w0; a[2][1] += v2 * w1;
        }
        int node = nb + w;
        size_t ob = (size_t)node * 384;
        float gv[3] = { g0, g1, g2 };
        #pragma unroll
        for (int cc = 0; cc < 2; ++cc) {
            int col = l + 64 * cc;
            float dot = a[0][cc] * g0 + a[1][cc] * g1 + a[2][cc] * g2;
            bool m = dot >= 0.f;
            #pragma unroll
            for (int d = 0; d < 3; ++d) {
                float lv = a[d][cc];
                vio[ob + d * 128 + col] = m ? lv : 0.5f * (lv + gv[d]);
            }
        }
    }
}

extern "C" void kernel_launch(void* const* d_in, const int* in_sizes, int n_in,
                              void* d_out, int out_size, void* d_ws, size_t ws_size,
                              hipStream_t stream)
{
    const float* x   = (const float*)d_in[0];
    const float* xde = (const float*)d_in[1];
    const float* vec = (const float*)d_in[2];
    const float* ef  = (const float*)d_in[3];
    const float* ev  = (const float*)d_in[4];
    const int*   eidx= (const int*)d_in[5];
    const float* Wd  = (const float*)d_in[6];
    const float* bd  = (const float*)d_in[7];
    const float* W1  = (const float*)d_in[8];
    const float* b1  = (const float*)d_in[9];
    const float* W2  = (const float*)d_in[10];
    const float* b2  = (const float*)d_in[11];
    const float* We  = (const float*)d_in[12];
    const float* be  = (const float*)d_in[13];
    const float* Wl  = (const float*)d_in[14];
    const float* Wg  = (const float*)d_in[15];

    // workspace: xd, xh only (153.6 MB). h1 staged in d_out's d_x region
    // (12.8 MB <= 25.6 MB), consumed before the memset below.
    float* xd = (float*)d_ws;                        // NN*384 f32
    float* xh = xd + (size_t)NN * 384;               // NN*384 f32
    float* h1 = (float*)d_out;                       // temp, NN*64 f32
    float* dx   = (float*)d_out;                     // NN*128 f32 accumulator
    float* dvec = dx + (size_t)NN * 128;             // NN*384 f32 accumulator

    k_h1<<<1563, 256, 0, stream>>>(x, W1, b1, h1);
    k_gemm384<128><<<1563, 256, 0, stream>>>(xde, Wd, bd, xd);
    k_gemm384<64><<<1563, 256, 0, stream>>>(h1, W2, b2, xh);
    hipMemsetAsync(d_out, 0, (size_t)out_size * sizeof(float), stream);
    k_edge<<<12500, 256, 0, stream>>>(ef, ev, eidx, We, be, xd, xh, vec, dx, dvec);
    k_act<<<3125, 256, 0, stream>>>(dvec, Wl, Wg);
}

// Round 3
// 1012.713 us; speedup vs baseline: 1.2008x; 1.2008x over previous
//
#include <hip/hip_runtime.h>
#include <math.h>

#define NN 50000
#define EE 400000
#define NBINS 50176   // 1024 * 49, >= NN

// ---------- K1: h1 = ScaledSiLU(x @ W_x1 + b_x1)  [NN,128]x[128,64] ----------
__global__ __launch_bounds__(256) void k_h1(
    const float* __restrict__ x, const float* __restrict__ W,
    const float* __restrict__ b, float* __restrict__ h1)
{
    __shared__ float xs[32 * 128];
    int t = threadIdx.x;
    int base = blockIdx.x * 32;
    const float4* xv = (const float4*)x;
    for (int idx = t; idx < 1024; idx += 256) {
        int r = idx >> 5, c = idx & 31;
        int row = base + r; if (row >= NN) row = NN - 1;
        ((float4*)xs)[r * 32 + c] = xv[(size_t)row * 32 + c];
    }
    __syncthreads();
    int c = t & 63, rr = t >> 6;
    float acc[8] = {};
    for (int k = 0; k < 128; ++k) {
        float wv = W[k * 64 + c];
        #pragma unroll
        for (int q = 0; q < 8; ++q) acc[q] += xs[(rr + 4 * q) * 128 + k] * wv;
    }
    float bb = b[c];
    #pragma unroll
    for (int q = 0; q < 8; ++q) {
        int row = base + rr + 4 * q;
        if (row < NN) {
            float z = acc[q] + bb;
            h1[(size_t)row * 64 + c] = z / (1.f + expf(-z)) * (1.f / 0.6f);  // ScaledSiLU
        }
    }
}

// ---------- K2: out[n,384] = A[n,K] @ W[K,384] + b  (f32) ----------
template <int K>
__global__ __launch_bounds__(256) void k_gemm384(
    const float* __restrict__ A, const float* __restrict__ W,
    const float* __restrict__ b, float* __restrict__ out)
{
    __shared__ float as[32 * K];
    int t = threadIdx.x;
    int base = blockIdx.x * 32;
    const float4* av = (const float4*)A;
    const int K4 = K / 4;
    for (int idx = t; idx < 32 * K4; idx += 256) {
        int r = idx / K4, c = idx % K4;
        int row = base + r; if (row >= NN) row = NN - 1;
        ((float4*)as)[r * K4 + c] = av[(size_t)row * K4 + c];
    }
    __syncthreads();
    int c = t & 63, rr = t >> 6;
    float acc[8][6] = {};
    for (int k = 0; k < K; ++k) {
        float wv[6];
        #pragma unroll
        for (int m = 0; m < 6; ++m) wv[m] = W[k * 384 + c + 64 * m];
        #pragma unroll
        for (int q = 0; q < 8; ++q) {
            float a = as[(rr + 4 * q) * K + k];
            #pragma unroll
            for (int m = 0; m < 6; ++m) acc[q][m] += a * wv[m];
        }
    }
    float bb[6];
    #pragma unroll
    for (int m = 0; m < 6; ++m) bb[m] = b[c + 64 * m];
    #pragma unroll
    for (int q = 0; q < 8; ++q) {
        int row = base + rr + 4 * q;
        if (row < NN) {
            #pragma unroll
            for (int m = 0; m < 6; ++m)
                out[(size_t)row * 384 + c + 64 * m] = acc[q][m] + bb[m];
        }
    }
}

// ---------- sort pipeline: counting sort of edges by destination i ----------
__global__ __launch_bounds__(256) void k_hist(
    const int* __restrict__ eidx, int* __restrict__ cnt)
{
    int e = blockIdx.x * 256 + threadIdx.x;
    if (e < EE) atomicAdd(&cnt[eidx[(size_t)EE + e]], 1);
}

// one block of 1024: exclusive scan of cnt[NBINS] -> off2
__global__ __launch_bounds__(1024) void k_scan(
    const int* __restrict__ cnt, int* __restrict__ off2)
{
    __shared__ int part[1024];
    int t = threadIdx.x;
    int base = t * 49;
    int s = 0;
    #pragma unroll 7
    for (int q = 0; q < 49; ++q) s += cnt[base + q];
    part[t] = s;
    __syncthreads();
    int mine = s;
    for (int d = 1; d < 1024; d <<= 1) {
        int v = (t >= d) ? part[t - d] : 0;
        __syncthreads();
        part[t] += v;
        __syncthreads();
    }
    int run = part[t] - mine;   // exclusive prefix at chunk start
    for (int q = 0; q < 49; ++q) { off2[base + q] = run; run += cnt[base + q]; }
}

__global__ __launch_bounds__(256) void k_scatter(
    const int* __restrict__ eidx, int* __restrict__ off2, int* __restrict__ perm)
{
    int e = blockIdx.x * 256 + threadIdx.x;
    if (e < EE) {
        int pos = atomicAdd(&off2[eidx[(size_t)EE + e]], 1);
        perm[pos] = e;
    }
}

// ---------- K3: sorted edges, fused rbf GEMV + msg + segmented scatter-add ----------
// Wave w owns sorted positions ebase+8w .. ebase+8w+7 (same destination i mostly).
__global__ __launch_bounds__(256) void k_edge_sorted(
    const float* __restrict__ ef, const float* __restrict__ ev,
    const int* __restrict__ eidx, const int* __restrict__ perm,
    const float* __restrict__ We, const float* __restrict__ be,
    const float* __restrict__ xd, const float* __restrict__ xh,
    const float* __restrict__ vec,
    float* __restrict__ dx, float* __restrict__ dvec)
{
    __shared__ float efs[32 * 64];
    __shared__ float evs[96];
    __shared__ int perm_s[32];
    __shared__ int js[32], is_[32];
    int t = threadIdx.x;
    int ebase = blockIdx.x * 32;
    if (t < 32) perm_s[t] = perm[ebase + t];
    __syncthreads();
    if (t < 32) { int e = perm_s[t]; js[t] = eidx[e]; is_[t] = eidx[(size_t)EE + e]; }
    if (t >= 128 && t < 224) {
        int q = t - 128;
        int e = perm_s[q / 3];
        evs[q] = ev[(size_t)e * 3 + q % 3];
    }
    const float4* efv = (const float4*)ef;
    for (int idx = t; idx < 512; idx += 256) {
        int r = idx >> 4;
        int e = perm_s[r];
        ((float4*)efs)[idx] = efv[(size_t)e * 16 + (idx & 15)];
    }
    __syncthreads();

    int c = t & 63, w = t >> 6;
    // rbf GEMV, register-blocked over the wave's 8 edges
    float acc[8][6] = {};
    for (int k = 0; k < 64; ++k) {
        float wv[6];
        #pragma unroll
        for (int m = 0; m < 6; ++m) wv[m] = We[k * 384 + c + 64 * m];
        #pragma unroll
        for (int r = 0; r < 8; ++r) {
            float f = efs[(8 * w + r) * 64 + k];   // wave-uniform -> LDS broadcast
            #pragma unroll
            for (int m = 0; m < 6; ++m) acc[r][m] += f * wv[m];
        }
    }
    float bb[6];
    #pragma unroll
    for (int m = 0; m < 6; ++m) bb[m] = be[c + 64 * m];

    const float IS3 = 0.57735026918962576f;   // 1/sqrt(3)
    const float ISH = 0.08838834764831845f;   // 1/sqrt(128)

    int curI = -1;
    float s[8];   // dvec d0c0,d0c1,d1c0,d1c1,d2c0,d2c1, dx c0, dx c1
    #pragma unroll
    for (int r = 0; r < 8; ++r) {
        int eL = 8 * w + r;
        int j = js[eL], i = is_[eL];
        size_t jb = (size_t)j * 384, ib = (size_t)i * 384;
        float msg[6];
        #pragma unroll
        for (int m = 0; m < 6; ++m) {
            int col = c + 64 * m;
            float rbf = acc[r][m] + bb[m];
            float xdv = xd[jb + col] + xd[ib + col];
            msg[m] = xh[jb + col] * xdv * rbf * IS3;
        }
        float cb[8];
        #pragma unroll
        for (int d = 0; d < 3; ++d) {
            float ed = evs[eL * 3 + d];
            float v0 = vec[jb + d * 128 + c];
            float v1 = vec[jb + d * 128 + c + 64];
            cb[2 * d]     = (msg[0] * v0 + msg[2] * ed) * ISH;
            cb[2 * d + 1] = (msg[1] * v1 + msg[3] * ed) * ISH;
        }
        cb[6] = msg[4]; cb[7] = msg[5];

        if (i != curI) {                        // wave-uniform branch
            if (curI >= 0) {
                size_t pb = (size_t)curI * 384;
                unsafeAtomicAdd(&dvec[pb + 0 * 128 + c],      s[0]);
                unsafeAtomicAdd(&dvec[pb + 0 * 128 + c + 64], s[1]);
                unsafeAtomicAdd(&dvec[pb + 1 * 128 + c],      s[2]);
                unsafeAtomicAdd(&dvec[pb + 1 * 128 + c + 64], s[3]);
                unsafeAtomicAdd(&dvec[pb + 2 * 128 + c],      s[4]);
                unsafeAtomicAdd(&dvec[pb + 2 * 128 + c + 64], s[5]);
                unsafeAtomicAdd(&dx[(size_t)curI * 128 + c],      s[6]);
                unsafeAtomicAdd(&dx[(size_t)curI * 128 + c + 64], s[7]);
            }
            curI = i;
            #pragma unroll
            for (int q = 0; q < 8; ++q) s[q] = cb[q];
        } else {
            #pragma unroll
            for (int q = 0; q < 8; ++q) s[q] += cb[q];
        }
    }
    {   // final flush (blocks are always full: 12500*32 == EE)
        size_t pb = (size_t)curI * 384;
        unsafeAtomicAdd(&dvec[pb + 0 * 128 + c],      s[0]);
        unsafeAtomicAdd(&dvec[pb + 0 * 128 + c + 64], s[1]);
        unsafeAtomicAdd(&dvec[pb + 1 * 128 + c],      s[2]);
        unsafeAtomicAdd(&dvec[pb + 1 * 128 + c + 64], s[3]);
        unsafeAtomicAdd(&dvec[pb + 2 * 128 + c],      s[4]);
        unsafeAtomicAdd(&dvec[pb + 2 * 128 + c + 64], s[5]);
        unsafeAtomicAdd(&dx[(size_t)curI * 128 + c],      s[6]);
        unsafeAtomicAdd(&dx[(size_t)curI * 128 + c + 64], s[7]);
    }
}

// ---------- K4: vector activation, in-place on d_vec region, one wave per node ----------
__global__ __launch_bounds__(256) void k_act(
    float* vio, const float* __restrict__ Wl, const float* __restrict__ Wg)
{
    __shared__ float vs[4 * 384];
    __shared__ float wg[128];
    int t = threadIdx.x;
    if (t < 128) wg[t] = Wg[t];
    int w = t >> 6, l = t & 63;
    for (int it = 0; it < 4; ++it) {
        __syncthreads();               // prior iter's readers done before vs overwrite
        int nb = blockIdx.x * 16 + it * 4;          // 3125*16 = 50000 exact
        const float4* vsrc = (const float4*)(vio + (size_t)nb * 384);
        float4* vdst = (float4*)vs;
        for (int idx = t; idx < 384; idx += 256) vdst[idx] = vsrc[idx];
        __syncthreads();
        const float* v = &vs[w * 384];
        float g0 = v[l] * wg[l] + v[l + 64] * wg[l + 64];
        float g1 = v[128 + l] * wg[l] + v[128 + l + 64] * wg[l + 64];
        float g2 = v[256 + l] * wg[l] + v[256 + l + 64] * wg[l + 64];
        #pragma unroll
        for (int off = 32; off > 0; off >>= 1) {
            g0 += __shfl_xor(g0, off, 64);
            g1 += __shfl_xor(g1, off, 64);
            g2 += __shfl_xor(g2, off, 64);
        }
        float a[3][2] = {};
        #pragma unroll 4
        for (int h = 0; h < 128; ++h) {
            float w0 = Wl[h * 128 + l];
            float w1 = Wl[h * 128 + l + 64];
            float v0 = v[h], v1 = v[128 + h], v2 = v[256 + h];
            a[0][0] += v0 * w0; a[0][1] += v0 * w1;
            a[1][0] += v1 * w0; a[1][1] += v1 * w1;
            a[2][0] += v2 * w0; a[2][1] += v2 * w1;
        }
        int node = nb + w;
        size_t ob = (size_t)node * 384;
        float gv[3] = { g0, g1, g2 };
        #pragma unroll
        for (int cc = 0; cc < 2; ++cc) {
            int col = l + 64 * cc;
            float dot = a[0][cc] * g0 + a[1][cc] * g1 + a[2][cc] * g2;
            bool m = dot >= 0.f;
            #pragma unroll
            for (int d = 0; d < 3; ++d) {
                float lv = a[d][cc];
                vio[ob + d * 128 + col] = m ? lv : 0.5f * (lv + gv[d]);
            }
        }
    }
}

extern "C" void kernel_launch(void* const* d_in, const int* in_sizes, int n_in,
                              void* d_out, int out_size, void* d_ws, size_t ws_size,
                              hipStream_t stream)
{
    const float* x   = (const float*)d_in[0];
    const float* xde = (const float*)d_in[1];
    const float* vec = (const float*)d_in[2];
    const float* ef  = (const float*)d_in[3];
    const float* ev  = (const float*)d_in[4];
    const int*   eidx= (const int*)d_in[5];
    const float* Wd  = (const float*)d_in[6];
    const float* bd  = (const float*)d_in[7];
    const float* W1  = (const float*)d_in[8];
    const float* b1  = (const float*)d_in[9];
    const float* W2  = (const float*)d_in[10];
    const float* b2  = (const float*)d_in[11];
    const float* We  = (const float*)d_in[12];
    const float* be  = (const float*)d_in[13];
    const float* Wl  = (const float*)d_in[14];
    const float* Wg  = (const float*)d_in[15];

    // ws: xd(76.8MB) + xh(76.8MB) + sort scratch (~2MB)
    float* xd  = (float*)d_ws;                       // NN*384 f32
    float* xh  = xd + (size_t)NN * 384;              // NN*384 f32
    int* cnt   = (int*)(xh + (size_t)NN * 384);      // NBINS
    int* off2  = cnt + NBINS;                        // NBINS
    int* perm  = off2 + NBINS;                       // EE
    float* h1  = (float*)d_out;                      // temp, overwritten by memset
    float* dx   = (float*)d_out;                     // NN*128 f32 accumulator
    float* dvec = dx + (size_t)NN * 128;             // NN*384 f32 accumulator

    // destination-sorted edge permutation (counting sort)
    hipMemsetAsync(cnt, 0, NBINS * sizeof(int), stream);
    k_hist<<<1563, 256, 0, stream>>>(eidx, cnt);
    k_scan<<<1, 1024, 0, stream>>>(cnt, off2);
    k_scatter<<<1563, 256, 0, stream>>>(eidx, off2, perm);

    k_h1<<<1563, 256, 0, stream>>>(x, W1, b1, h1);
    k_gemm384<128><<<1563, 256, 0, stream>>>(xde, Wd, bd, xd);
    k_gemm384<64><<<1563, 256, 0, stream>>>(h1, W2, b2, xh);
    hipMemsetAsync(d_out, 0, (size_t)out_size * sizeof(float), stream);
    k_edge_sorted<<<12500, 256, 0, stream>>>(ef, ev, eidx, perm, We, be, xd, xh, vec, dx, dvec);
    k_act<<<3125, 256, 0, stream>>>(dvec, Wl, Wg);
}